// Round 10
// baseline (337.027 us; speedup 1.0000x reference)
//
#include <hip/hip_runtime.h>
#include <hip/hip_bf16.h>

#define B_ 64
#define N_ 4096
#define F_ 512
#define D_ 256
#define BM 64
#define APAD 520                 // halves per LDS row (1040 B)
#define NCHUNK (N_ / BM)         // 64 tiles per batch
#define GT 16                    // tiles per block
#define NBLK (B_ * NCHUNK / GT)  // 256 blocks = 1/CU

typedef __attribute__((ext_vector_type(8))) short short8;
typedef __attribute__((ext_vector_type(4))) float f32x4;

__device__ __forceinline__ unsigned short f2bf(float f) {
  unsigned int u = __float_as_uint(f);
  u += 0x7FFFu + ((u >> 16) & 1u);   // RNE round to bf16
  return (unsigned short)(u >> 16);
}

__device__ __forceinline__ unsigned int pk2bf(float x, float y) {
  float2 f; f.x = x; f.y = y;
  __hip_bfloat162 h = __float22bfloat162_rn(f);   // v_cvt_pk_bf16_f32
  union { __hip_bfloat162 h2; unsigned int u; } cv; cv.h2 = h;
  return cv.u;                                    // x in low 16 bits
}

__device__ __forceinline__ float fast_tanh(float x) {
  float e = __expf(-2.0f * fabsf(x));
  float t = (1.0f - e) / (1.0f + e);
  return copysignf(t, x);
}

#define SBAR                                                                   \
  do {                                                                         \
    __builtin_amdgcn_sched_barrier(0);                                         \
    __builtin_amdgcn_s_barrier();                                              \
    __builtin_amdgcn_sched_barrier(0);                                         \
  } while (0)

#define LGKM0                                                                  \
  do {                                                                         \
    asm volatile("s_waitcnt lgkmcnt(0)" ::: "memory");                         \
    __builtin_amdgcn_sched_barrier(0);                                         \
  } while (0)

#define VMC4                                                                   \
  do {                                                                         \
    asm volatile("s_waitcnt vmcnt(4)" ::: "memory");                           \
    __builtin_amdgcn_sched_barrier(0);                                         \
  } while (0)

// ---- prep: W_img f32 [256][512] -> bf16 in exact MFMA B-fragment order.
// frag g = q*16 + d16 (q = K-step-32 idx 0..15): idx = (g*64 + lane)*8 + e
__global__ void prep_w_kernel(const float* __restrict__ Wimg,
                              unsigned short* __restrict__ wfrag) {
  int d = blockIdx.x;        // 0..255
  int f = threadIdx.x;       // 0..511
  int q = f >> 5, lg = (f >> 3) & 3, e = f & 7;
  int lr = d & 15, d16 = d >> 4;
  int lane = lg * 16 + lr;
  int idx = ((q * 16 + d16) * 64 + lane) * 8 + e;
  wfrag[idx] = f2bf(Wimg[d * F_ + f]);
}

// ---- prep: proj_hidden[b][d]
__global__ void prep_ph_kernel(const float* __restrict__ hid,
                               const float* __restrict__ Whid,
                               float* __restrict__ ph) {
  int b = blockIdx.x, d = threadIdx.x;  // 64 x 256
  const float4* hv = (const float4*)(hid + b * F_);
  const float4* wv = (const float4*)(Whid + d * F_);
  float acc = 0.f;
#pragma unroll 4
  for (int i = 0; i < 128; i++) {
    float4 h = hv[i], w = wv[i];
    acc += h.x * w.x + h.y * w.y + h.z * w.z + h.w * w.w;
  }
  ph[b * D_ + d] = acc;
}

// ---- fused: m97-class GEMM (4x4 acc, DMA B) + tanh + score + ctx partial
__global__ __launch_bounds__(256, 1) void fused_kernel(
    const float* __restrict__ feat, const unsigned short* __restrict__ wfrag,
    const float* __restrict__ ph, const float* __restrict__ wscore,
    float* __restrict__ expw, float2* __restrict__ meta,
    float* __restrict__ part) {
  __shared__ unsigned short Afull[BM * APAD];   // 65 KiB resident bf16 tile
  __shared__ unsigned short Bst[2][16384];      // 64 KiB B dbuf, frag-linear
  __shared__ float red[BM][4];
  __shared__ float sbuf[BM];
  __shared__ float ewf[BM];

  int tid = threadIdx.x;
  int lane = tid & 63, wn = tid >> 6;      // 4 waves; wave wn owns cols [wn*64, +64)
  int lr = lane & 15, lg = lane >> 4;

  int blk = blockIdx.x;                    // 256
  int b = blk >> 2, j = blk & 3;           // 4 blocks/batch, 16 tiles each

  float ph4[4], ws4[4];
#pragma unroll
  for (int n = 0; n < 4; n++) {
    int d = wn * 64 + n * 16 + lr;
    ph4[n] = ph[b * D_ + d];
    ws4[n] = wscore[d];
  }

  // A staging: per kt 64 rows x 64 f32 cols = 16 KiB; thread: row=tid>>2, 16 f32
  int r_ = tid >> 2, c16 = (tid & 3) * 16;
  const float* arow = feat + ((size_t)b * N_ + (size_t)j * GT * BM) * F_;

  float4 rs0_[4], rs1_[4];

#define LOADS(buf, ptr, kt_)                                                   \
  _Pragma("unroll") for (int i = 0; i < 4; i++)                                \
      buf[i] = *(const float4*)((ptr) + (size_t)r_ * F_ + (kt_)*64 + c16 + i * 4);

#define CVT(buf, kt_)                                                          \
  _Pragma("unroll") for (int i = 0; i < 4; i++) {                              \
    unsigned int p0 = pk2bf(buf[i].x, buf[i].y);                               \
    unsigned int p1 = pk2bf(buf[i].z, buf[i].w);                               \
    *(uint2*)(Afull + r_ * APAD + (kt_)*64 + c16 + i * 4) = make_uint2(p0, p1);\
  }

// DMA B(kt) into Bst[bs]: 32 frags x 1 KiB; wave wn stages frags wn*8..+8
#define DMAB(bs, kt_)                                                          \
  do {                                                                         \
    __builtin_amdgcn_sched_barrier(0);                                         \
    _Pragma("unroll") for (int i = 0; i < 8; i++) {                            \
      int fg = wn * 8 + i;                                                     \
      const char* gsrc = (const char*)wfrag + ((size_t)(kt_)*32 + fg) * 1024 + lane * 16; \
      char* ldst = (char*)&Bst[bs][0] + fg * 1024 + lane * 16;                 \
      __builtin_amdgcn_global_load_lds(                                        \
          (const __attribute__((address_space(1))) void*)gsrc,                 \
          (__attribute__((address_space(3))) void*)ldst, 16, 0, 0);            \
    }                                                                          \
    __builtin_amdgcn_sched_barrier(0);                                         \
  } while (0)

// one K-step-32 (ql in 0..1): 4 A frags + 4 B frags (LDS) + 16 MFMA
#define QSTEP(kt_, ql_, bs)                                                    \
  {                                                                            \
    short8 bf[4], af[4];                                                       \
    _Pragma("unroll") for (int n = 0; n < 4; n++)                              \
        bf[n] = *(const short8*)(&Bst[bs][(((ql_)*16 + wn * 4 + n) * 64 + lane) * 8]); \
    _Pragma("unroll") for (int m = 0; m < 4; m++)                              \
        af[m] = *(const short8*)(Afull + (m * 16 + lr) * APAD + (kt_)*64 + (ql_)*32 + lg * 8); \
    _Pragma("unroll") for (int m = 0; m < 4; m++)                              \
      _Pragma("unroll") for (int n = 0; n < 4; n++)                            \
        acc[m][n] = __builtin_amdgcn_mfma_f32_16x16x32_bf16(af[m], bf[n], acc[m][n], 0, 0, 0); \
  }

#define COMPUTE(kt_, bs) { QSTEP(kt_, 0, bs); QSTEP(kt_, 1, bs); }

  // block prologue: B(kt0) DMA + A kt0/kt1 loads
  DMAB(0, 0);
  LOADS(rs0_, arow, 0);
  LOADS(rs1_, arow, 1);

#pragma unroll 1
  for (int t = 0; t < GT; t++) {
    const float* nrow = (t < GT - 1) ? (arow + (size_t)BM * F_) : arow;
    f32x4 acc[4][4];
#pragma unroll
    for (int m = 0; m < 4; m++)
#pragma unroll
      for (int n = 0; n < 4; n++) acc[m][n] = (f32x4)0.f;

    // tile top: publish A kt0 (auto counted-vmcnt), drain DMA b0
    CVT(rs0_, 0); LGKM0; VMC4; SBAR;
    // 8 phases; per phase: DMA next-B, load A kt+2, compute kt, write A kt+1
    DMAB(1, 1); LOADS(rs0_, arow, 2); COMPUTE(0, 0); CVT(rs1_, 1); LGKM0; VMC4; SBAR;
    DMAB(0, 2); LOADS(rs1_, arow, 3); COMPUTE(1, 1); CVT(rs0_, 2); LGKM0; VMC4; SBAR;
    DMAB(1, 3); LOADS(rs0_, arow, 4); COMPUTE(2, 0); CVT(rs1_, 3); LGKM0; VMC4; SBAR;
    DMAB(0, 4); LOADS(rs1_, arow, 5); COMPUTE(3, 1); CVT(rs0_, 4); LGKM0; VMC4; SBAR;
    DMAB(1, 5); LOADS(rs0_, arow, 6); COMPUTE(4, 0); CVT(rs1_, 5); LGKM0; VMC4; SBAR;
    DMAB(0, 6); LOADS(rs1_, arow, 7); COMPUTE(5, 1); CVT(rs0_, 6); LGKM0; VMC4; SBAR;
    DMAB(1, 7); LOADS(rs0_, nrow, 0); COMPUTE(6, 0); CVT(rs1_, 7); LGKM0; VMC4; SBAR;
    DMAB(0, 8); LOADS(rs1_, nrow, 1); COMPUTE(7, 1); SBAR;
    // exit: rs0_/rs1_ hold next tile kt0/kt1; Bst[0] DMA for next kt0 in flight
    // (DMAB(0,8) reads wfrag past kt7 only via kt_*32: 8*32=256 frags = exactly
    //  the end -> wrap to 0 to stay in-bounds)

    // ---- scores: s[row] = sum_d tanh(proj + ph) * wscore
#pragma unroll
    for (int m = 0; m < 4; m++) {
#pragma unroll
      for (int jj = 0; jj < 4; jj++) {
        float p = 0.f;
#pragma unroll
        for (int n = 0; n < 4; n++)
          p += fast_tanh(acc[m][n][jj] + ph4[n]) * ws4[n];
        p += __shfl_xor(p, 1);
        p += __shfl_xor(p, 2);
        p += __shfl_xor(p, 4);
        p += __shfl_xor(p, 8);
        if (lr == 0) red[m * 16 + lg * 4 + jj][wn] = p;
      }
    }
    LGKM0; SBAR;
    if (tid < BM) sbuf[tid] = red[tid][0] + red[tid][1] + red[tid][2] + red[tid][3];
    LGKM0; SBAR;

    int tile = j * GT + t;
    int n0 = tile * BM;
    float mb = -1e30f;
#pragma unroll
    for (int r = 0; r < BM; r++) mb = fmaxf(mb, sbuf[r]);
    if (tid < BM) {
      float e = __expf(sbuf[tid] - mb);
      ewf[tid] = e;
      expw[b * N_ + n0 + tid] = e;
      float l = e;
#pragma unroll
      for (int o = 1; o < 64; o <<= 1) l += __shfl_xor(l, o);
      if (tid == 0) meta[b * NCHUNK + tile] = make_float2(mb, l);
    }
    LGKM0; SBAR;

    // ---- context partial from resident bf16 tile (256 thr x 2 cols)
    {
      int f0 = tid * 2;
      float a0 = 0.f, a1 = 0.f;
#pragma unroll 8
      for (int r = 0; r < BM; r++) {
        float w = ewf[r];
        unsigned int v = *(const unsigned int*)(Afull + r * APAD + f0);
        a0 += w * __uint_as_float(v << 16);
        a1 += w * __uint_as_float(v & 0xffff0000u);
      }
      float2 o; o.x = a0; o.y = a1;
      *(float2*)(part + (size_t)(b * NCHUNK + tile) * F_ + f0) = o;
    }
    SBAR;   // tile LDS free for next tile's CVT

    arow = nrow;
  }
}

// ---- finalize per batch: global softmax merge + context combine + weights
__global__ void finalize_kernel(const float* __restrict__ part,
                                const float2* __restrict__ meta,
                                const float* __restrict__ expw,
                                float* __restrict__ ctx,
                                float* __restrict__ wout) {
  __shared__ float sm[NCHUNK], sl[NCHUNK], se[NCHUNK];
  int b = blockIdx.x, t = threadIdx.x;   // 512 threads
  if (t < NCHUNK) {
    float2 ml = meta[b * NCHUNK + t];
    sm[t] = ml.x;
    sl[t] = ml.y;
  }
  __syncthreads();
  float M = -1e30f;
#pragma unroll 8
  for (int i = 0; i < NCHUNK; i++) M = fmaxf(M, sm[i]);
  float Z = 0.f;
#pragma unroll 8
  for (int i = 0; i < NCHUNK; i++) Z += sl[i] * __expf(sm[i] - M);
  if (t < NCHUNK) se[t] = __expf(sm[t] - M);
  __syncthreads();
  float invZ = 1.0f / Z;
  float acc = 0.f;
#pragma unroll 8
  for (int i = 0; i < NCHUNK; i++) acc += part[(size_t)(b * NCHUNK + i) * F_ + t] * se[i];
  ctx[b * F_ + t] = acc * invZ;
#pragma unroll
  for (int k = 0; k < 8; k++) {
    int n = k * 512 + t;
    wout[b * N_ + n] = expw[b * N_ + n] * se[n >> 6] * invZ;
  }
}

extern "C" void kernel_launch(void* const* d_in, const int* in_sizes, int n_in,
                              void* d_out, int out_size, void* d_ws, size_t ws_size,
                              hipStream_t stream) {
  const float* feat   = (const float*)d_in[0];   // [64,4096,512]
  const float* hid    = (const float*)d_in[1];   // [64,512]
  const float* Wimg   = (const float*)d_in[2];   // [256,512]
  const float* Whid   = (const float*)d_in[3];   // [256,512]
  const float* Wscore = (const float*)d_in[4];   // [1,256]

  float* ctx  = (float*)d_out;            // [64,512]
  float* wout = (float*)d_out + B_ * F_;  // [64,4096]

  // workspace: wfrag gets 2x256 KiB so the tail DMAB(0,8) read stays in-bounds
  unsigned short* wfrag = (unsigned short*)d_ws;                 // 512 KiB
  float*  ph    = (float*)((char*)d_ws + 524288);                // 64 KiB
  float*  expw  = (float*)((char*)d_ws + 589824);                // 1 MiB
  float2* meta  = (float2*)((char*)d_ws + 1638400);              // 32 KiB
  float*  part  = (float*)((char*)d_ws + 1671168);               // 8 MiB

  prep_w_kernel<<<D_, F_, 0, stream>>>(Wimg, wfrag);
  // duplicate wfrag into its second half so kt=8 (wrap) DMA reads valid data
  hipMemcpyAsync((char*)d_ws + 262144, d_ws, 262144, hipMemcpyDeviceToDevice, stream);
  prep_ph_kernel<<<B_, D_, 0, stream>>>(hid, Whid, ph);
  fused_kernel<<<NBLK, 256, 0, stream>>>(feat, wfrag, ph, Wscore, expw, meta, part);
  finalize_kernel<<<B_, 512, 0, stream>>>(part, meta, expw, ctx, wout);
}

// Round 11
// 250.952 us; speedup vs baseline: 1.3430x; 1.3430x over previous
//
#include <hip/hip_runtime.h>
#include <hip/hip_bf16.h>

#define B_ 64
#define N_ 4096
#define F_ 512
#define D_ 256
#define BM 32
#define APAD 520                 // halves per LDS row (1040 B)
#define NCHUNK (N_ / BM)         // 128 chunks per batch
#define GT 4                     // tiles per block (pipelined)
#define NGRP (NCHUNK / GT)       // 32 groups per batch
#define NBLK (B_ * NGRP)         // 2048 blocks

typedef __attribute__((ext_vector_type(8))) short short8;
typedef __attribute__((ext_vector_type(4))) float f32x4;

__device__ __forceinline__ unsigned short f2bf(float f) {
  unsigned int u = __float_as_uint(f);
  u += 0x7FFFu + ((u >> 16) & 1u);   // RNE round to bf16
  return (unsigned short)(u >> 16);
}

__device__ __forceinline__ unsigned int pk2bf(float x, float y) {
  float2 f; f.x = x; f.y = y;
  __hip_bfloat162 h = __float22bfloat162_rn(f);   // v_cvt_pk_bf16_f32
  union { __hip_bfloat162 h2; unsigned int u; } cv; cv.h2 = h;
  return cv.u;                                    // x in low 16 bits
}

__device__ __forceinline__ float rcp_f(float x) {
  float r; asm("v_rcp_f32 %0, %1" : "=v"(r) : "v"(x)); return r;
}
__device__ __forceinline__ float exp2_f(float x) {
  float r; asm("v_exp_f32 %0, %1" : "=v"(r) : "v"(x)); return r;
}
__device__ __forceinline__ float fast_tanh(float x) {
  float a = fabsf(x);
  float e = exp2_f(-2.885390082f * a);     // e^{-2a}
  float t = (1.f - e) * rcp_f(1.f + e);
  return copysignf(t, x);
}

#define SBAR                                                                   \
  do {                                                                         \
    __builtin_amdgcn_sched_barrier(0);                                         \
    __builtin_amdgcn_s_barrier();                                              \
    __builtin_amdgcn_sched_barrier(0);                                         \
  } while (0)

#define LGKM0                                                                  \
  do {                                                                         \
    asm volatile("s_waitcnt lgkmcnt(0)" ::: "memory");                         \
    __builtin_amdgcn_sched_barrier(0);                                         \
  } while (0)

// ---- prep: W_img f32 [256][512] -> bf16 in exact MFMA B-fragment order.
// frag g = q*16 + d16 (q = K-step-32 idx 0..15): idx = (g*64 + lane)*8 + e
__global__ void prep_w_kernel(const float* __restrict__ Wimg,
                              unsigned short* __restrict__ wfrag) {
  int d = blockIdx.x;        // 0..255
  int f = threadIdx.x;       // 0..511
  int q = f >> 5, lg = (f >> 3) & 3, e = f & 7;
  int lr = d & 15, d16 = d >> 4;
  int lane = lg * 16 + lr;
  int idx = ((q * 16 + d16) * 64 + lane) * 8 + e;
  wfrag[idx] = f2bf(Wimg[d * F_ + f]);
}

// ---- prep: proj_hidden[b][d]
__global__ void prep_ph_kernel(const float* __restrict__ hid,
                               const float* __restrict__ Whid,
                               float* __restrict__ ph) {
  int b = blockIdx.x, d = threadIdx.x;  // 64 x 256
  const float4* hv = (const float4*)(hid + b * F_);
  const float4* wv = (const float4*)(Whid + d * F_);
  float acc = 0.f;
#pragma unroll 4
  for (int i = 0; i < 128; i++) {
    float4 h = hv[i], w = wv[i];
    acc += h.x * w.x + h.y * w.y + h.z * w.z + h.w * w.w;
  }
  ph[b * D_ + d] = acc;
}

// ---- fused: pipelined tiles — tile t epilogue overlaps tile t+1 GEMM
__global__ __launch_bounds__(512, 2) void fused_kernel(
    const float* __restrict__ feat, const unsigned short* __restrict__ wfrag,
    const float* __restrict__ ph, const float* __restrict__ wscore,
    float* __restrict__ expw, float2* __restrict__ meta,
    float* __restrict__ part) {
  __shared__ unsigned short Afull[2][BM * APAD];  // 2 x 33.3 KiB A dbuf
  __shared__ float red[BM][8];
  __shared__ float sbuf[BM];
  __shared__ float ewf[BM];

  int tid = threadIdx.x;
  int lane = tid & 63, wv = tid >> 6;      // 8 waves; wave wv owns cols [wv*32,+32)
  int lr = lane & 15, lg = lane >> 4;
  int wv2 = wv * 2;

  int blk = blockIdx.x;                    // 2048
  int b = blk >> 5, g = blk & 31;          // 32 groups/batch, GT tiles each

  const float* base = feat + ((size_t)b * N_ + (size_t)g * GT * BM) * F_;

  float ph2[2], ws2[2];
#pragma unroll
  for (int n = 0; n < 2; n++) {
    int d = wv * 32 + n * 16 + lr;
    ph2[n] = ph[b * D_ + d];
    ws2[n] = wscore[d];
  }

  // staging map per phase (128 f32 cols): thread covers rows prow, prow+16
  int prow = tid >> 5;        // 0..15
  int pcol = tid & 31;        // float4 col 0..31 within phase

  float4 rs0[2], rs1[2];

#define LOADP(buf, ptr, p_)                                                    \
  do {                                                                         \
    buf[0] = *(const float4*)((ptr) + (size_t)prow * F_ + (p_)*128 + pcol * 4);\
    buf[1] = *(const float4*)((ptr) + (size_t)(prow + 16) * F_ + (p_)*128 + pcol * 4); \
  } while (0)

#define CVTP(ab_, buf, p_)                                                     \
  do {                                                                         \
    _Pragma("unroll") for (int i = 0; i < 2; i++) {                            \
      uint2 w_;                                                                \
      w_.x = pk2bf(buf[i].x, buf[i].y);                                        \
      w_.y = pk2bf(buf[i].z, buf[i].w);                                        \
      *(uint2*)(&Afull[ab_][(prow + i * 16) * APAD + (p_)*128 + pcol * 4]) = w_; \
    }                                                                          \
  } while (0)

  f32x4 acc00 = (f32x4)0.f, acc01 = (f32x4)0.f, acc10 = (f32x4)0.f, acc11 = (f32x4)0.f;
  f32x4 accP00 = (f32x4)0.f, accP01 = (f32x4)0.f, accP10 = (f32x4)0.f, accP11 = (f32x4)0.f;

#define QQ(ab_, q_)                                                            \
  do {                                                                         \
    short8 bf0 = *(const short8*)(wfrag + (size_t)(((q_)*16 + wv2 + 0) * 64 + lane) * 8); \
    short8 bf1 = *(const short8*)(wfrag + (size_t)(((q_)*16 + wv2 + 1) * 64 + lane) * 8); \
    short8 af0 = *(const short8*)(&Afull[ab_][lr * APAD + (q_)*32 + lg * 8]);  \
    short8 af1 = *(const short8*)(&Afull[ab_][(16 + lr) * APAD + (q_)*32 + lg * 8]); \
    acc00 = __builtin_amdgcn_mfma_f32_16x16x32_bf16(af0, bf0, acc00, 0, 0, 0); \
    acc01 = __builtin_amdgcn_mfma_f32_16x16x32_bf16(af0, bf1, acc01, 0, 0, 0); \
    acc10 = __builtin_amdgcn_mfma_f32_16x16x32_bf16(af1, bf0, acc10, 0, 0, 0); \
    acc11 = __builtin_amdgcn_mfma_f32_16x16x32_bf16(af1, bf1, acc11, 0, 0, 0); \
  } while (0)

#define QQ4(ab_, p_) { QQ(ab_, (p_)*4 + 0); QQ(ab_, (p_)*4 + 1); QQ(ab_, (p_)*4 + 2); QQ(ab_, (p_)*4 + 3); }

// epilogue phase 0: tanh + intra-wave reduce (prev tile's acc, registers only)
#define EPI0()                                                                 \
  do {                                                                         \
    _Pragma("unroll") for (int j = 0; j < 4; j++) {                            \
      float p0 = fast_tanh(accP00[j] + ph2[0]) * ws2[0] +                      \
                 fast_tanh(accP01[j] + ph2[1]) * ws2[1];                       \
      float p1 = fast_tanh(accP10[j] + ph2[0]) * ws2[0] +                      \
                 fast_tanh(accP11[j] + ph2[1]) * ws2[1];                       \
      p0 += __shfl_xor(p0, 1); p0 += __shfl_xor(p0, 2);                        \
      p0 += __shfl_xor(p0, 4); p0 += __shfl_xor(p0, 8);                        \
      p1 += __shfl_xor(p1, 1); p1 += __shfl_xor(p1, 2);                        \
      p1 += __shfl_xor(p1, 4); p1 += __shfl_xor(p1, 8);                        \
      if (lr == 0) {                                                           \
        red[lg * 4 + j][wv] = p0;                                              \
        red[16 + lg * 4 + j][wv] = p1;                                         \
      }                                                                        \
    }                                                                          \
  } while (0)

#define EPI1()                                                                 \
  do {                                                                         \
    if (tid < BM)                                                              \
      sbuf[tid] = red[tid][0] + red[tid][1] + red[tid][2] + red[tid][3] +      \
                  red[tid][4] + red[tid][5] + red[tid][6] + red[tid][7];       \
  } while (0)

#define EPI2(cp_)                                                              \
  do {                                                                         \
    float mb_ = -1e30f;                                                        \
    _Pragma("unroll") for (int r = 0; r < BM; r++) mb_ = fmaxf(mb_, sbuf[r]);  \
    if (tid < BM) {                                                            \
      float e_ = __expf(sbuf[tid] - mb_);                                      \
      ewf[tid] = e_;                                                           \
      expw[b * N_ + (cp_)*BM + tid] = e_;                                      \
      float l_ = e_;                                                           \
      l_ += __shfl_xor(l_, 1); l_ += __shfl_xor(l_, 2);                        \
      l_ += __shfl_xor(l_, 4); l_ += __shfl_xor(l_, 8);                        \
      l_ += __shfl_xor(l_, 16);                                                \
      if (tid == 0) meta[b * NCHUNK + (cp_)] = make_float2(mb_, l_);           \
    }                                                                          \
  } while (0)

// epilogue phase 3: ctx partial from the PREVIOUS A buffer (col = tid)
#define EPI3(cp_, pb_)                                                         \
  do {                                                                         \
    float a_ = 0.f;                                                            \
    int ca_ = tid & ~1;                                                        \
    _Pragma("unroll") for (int r = 0; r < BM; r++) {                           \
      unsigned int v_ = *(const unsigned int*)(&Afull[pb_][r * APAD + ca_]);   \
      a_ += ewf[r] * __uint_as_float((tid & 1) ? (v_ & 0xffff0000u) : (v_ << 16)); \
    }                                                                          \
    part[(size_t)(b * NCHUNK + (cp_)) * F_ + tid] = a_;                        \
  } while (0)

  // block prologue: tile 0 phases 0,1 in flight
  LOADP(rs0, base, 0);
  LOADP(rs1, base, 1);

#pragma unroll 1
  for (int t = 0; t < GT; t++) {
    int ab = t & 1, pb = ab ^ 1;
    const float* arow = base + (size_t)t * BM * F_;
    const float* nrow = (t < GT - 1) ? (arow + (size_t)BM * F_) : arow;
    int cp = g * GT + t - 1;
    bool hp = (t > 0);

    CVTP(ab, rs0, 0); LGKM0; SBAR;
    LOADP(rs0, arow, 2); if (hp) EPI0();        QQ4(ab, 0); CVTP(ab, rs1, 1); LGKM0; SBAR;
    LOADP(rs1, arow, 3); if (hp) EPI1();        QQ4(ab, 1); CVTP(ab, rs0, 2); LGKM0; SBAR;
    LOADP(rs0, nrow, 0); if (hp) EPI2(cp);      QQ4(ab, 2); CVTP(ab, rs1, 3); LGKM0; SBAR;
    LOADP(rs1, nrow, 1); if (hp) EPI3(cp, pb);  QQ4(ab, 3); SBAR;

    // hand acc to the next tile's epilogue; restart accumulation
    accP00 = acc00; accP01 = acc01; accP10 = acc10; accP11 = acc11;
    acc00 = (f32x4)0.f; acc01 = (f32x4)0.f; acc10 = (f32x4)0.f; acc11 = (f32x4)0.f;
  }

  // drain: epilogue of the last tile
  {
    int cp = g * GT + GT - 1;
    int pb = (GT - 1) & 1;
    EPI0(); LGKM0; SBAR;
    EPI1(); LGKM0; SBAR;
    EPI2(cp); LGKM0; SBAR;
    EPI3(cp, pb);
  }
}

// ---- finalize per batch: global softmax merge + context combine + weights
__global__ void finalize_kernel(const float* __restrict__ part,
                                const float2* __restrict__ meta,
                                const float* __restrict__ expw,
                                float* __restrict__ ctx,
                                float* __restrict__ wout) {
  __shared__ float sm[NCHUNK], sl[NCHUNK], se[NCHUNK];
  int b = blockIdx.x, t = threadIdx.x;   // 512 threads
  if (t < NCHUNK) {
    float2 ml = meta[b * NCHUNK + t];
    sm[t] = ml.x;
    sl[t] = ml.y;
  }
  __syncthreads();
  float M = -1e30f;
#pragma unroll 8
  for (int i = 0; i < NCHUNK; i++) M = fmaxf(M, sm[i]);
  float Z = 0.f;
#pragma unroll 8
  for (int i = 0; i < NCHUNK; i++) Z += sl[i] * __expf(sm[i] - M);
  if (t < NCHUNK) se[t] = __expf(sm[t] - M);
  __syncthreads();
  float invZ = 1.0f / Z;
  float acc = 0.f;
#pragma unroll 8
  for (int i = 0; i < NCHUNK; i++) acc += part[(size_t)(b * NCHUNK + i) * F_ + t] * se[i];
  ctx[b * F_ + t] = acc * invZ;
#pragma unroll
  for (int k = 0; k < 8; k++) {
    int n = k * 512 + t;
    wout[b * N_ + n] = expw[b * N_ + n] * se[n >> 5] * invZ;
  }
}

extern "C" void kernel_launch(void* const* d_in, const int* in_sizes, int n_in,
                              void* d_out, int out_size, void* d_ws, size_t ws_size,
                              hipStream_t stream) {
  const float* feat   = (const float*)d_in[0];   // [64,4096,512]
  const float* hid    = (const float*)d_in[1];   // [64,512]
  const float* Wimg   = (const float*)d_in[2];   // [256,512]
  const float* Whid   = (const float*)d_in[3];   // [256,512]
  const float* Wscore = (const float*)d_in[4];   // [1,256]

  float* ctx  = (float*)d_out;            // [64,512]
  float* wout = (float*)d_out + B_ * F_;  // [64,4096]

  // workspace layout
  unsigned short* wfrag = (unsigned short*)d_ws;                 // 256 KiB
  float*  ph    = (float*)((char*)d_ws + 262144);                // 64 KiB
  float*  expw  = (float*)((char*)d_ws + 327680);                // 1 MiB
  float2* meta  = (float2*)((char*)d_ws + 1376256);              // 64 KiB
  float*  part  = (float*)((char*)d_ws + 1441792);               // 16 MiB

  prep_w_kernel<<<D_, F_, 0, stream>>>(Wimg, wfrag);
  prep_ph_kernel<<<B_, D_, 0, stream>>>(hid, Whid, ph);
  fused_kernel<<<NBLK, 512, 0, stream>>>(feat, wfrag, ph, Wscore, expw, meta, part);
  finalize_kernel<<<B_, 512, 0, stream>>>(part, meta, expw, ctx, wout);
}